// Round 2
// baseline (433.669 us; speedup 1.0000x reference)
//
#include <hip/hip_runtime.h>

#define DD   768
#define OUTN 196
#define MT   16        // rows per block
#define APAD 776       // LDS row stride (fp16 elems): 388 dwords, %32==4 -> min 2-way aliasing on b128 reads (free, m136)
#define KT   24        // 768 / 32

typedef __attribute__((ext_vector_type(8))) _Float16 halfx8;
typedef __attribute__((ext_vector_type(4))) _Float16 halfx4;
typedef __attribute__((ext_vector_type(4))) float    f32x4;

// Convert W (196x768 fp32, row-major [n][k]) to fp16 in workspace. Row-major
// [n][k] is exactly the B^T layout the MFMA B-fragment wants (8 consecutive k).
__global__ __launch_bounds__(256) void wprep_kernel(const float* __restrict__ W,
                                                    _Float16* __restrict__ Wh) {
    int i = blockIdx.x * 256 + threadIdx.x;
    if (i < OUTN * DD) Wh[i] = (_Float16)W[i];
}

__global__ __launch_bounds__(256) void fused_ln_linear(
    const float* __restrict__ x, const float* __restrict__ gamma,
    const float* __restrict__ beta, const _Float16* __restrict__ Wh,
    const float* __restrict__ bias, float* __restrict__ out)
{
    __shared__ _Float16 Ahi[MT * APAD];   // 24,832 B
    __shared__ _Float16 Alo[MT * APAD];   // 24,832 B  (total 49,664 B)

    const int tid  = threadIdx.x;
    const int wv   = tid >> 6;
    const int lane = tid & 63;
    const long row0 = (long)blockIdx.x * MT;

    // Per-lane gamma/beta columns are fixed: d = c*256 + lane*4
    float4 g[3], be[3];
#pragma unroll
    for (int c = 0; c < 3; ++c) {
        const int d0 = c * 256 + lane * 4;
        g[c]  = *(const float4*)(gamma + d0);
        be[c] = *(const float4*)(beta  + d0);
    }

    // ---------- Phase 1: LayerNorm, 4 rows per wave, fp16 hi/lo -> LDS ------
    {
        float4 xv[4][3];
#pragma unroll
        for (int t = 0; t < 4; ++t) {
            const float* xp = x + (row0 + wv * 4 + t) * DD;
#pragma unroll
            for (int c = 0; c < 3; ++c)
                xv[t][c] = *(const float4*)(xp + c * 256 + lane * 4);
        }
#pragma unroll
        for (int t = 0; t < 4; ++t) {
            float s = 0.f, ss = 0.f;
#pragma unroll
            for (int c = 0; c < 3; ++c) {
                const float4 v = xv[t][c];
                s  += v.x + v.y + v.z + v.w;
                ss += v.x * v.x + v.y * v.y + v.z * v.z + v.w * v.w;
            }
#pragma unroll
            for (int off = 32; off > 0; off >>= 1) {
                s  += __shfl_xor(s,  off);
                ss += __shfl_xor(ss, off);
            }
            const float mean = s * (1.f / DD);
            const float var  = ss * (1.f / DD) - mean * mean;
            const float rstd = rsqrtf(var + 1e-6f);
            const int r = wv * 4 + t;
#pragma unroll
            for (int c = 0; c < 3; ++c) {
                const float4 v = xv[t][c];
                float y0 = (v.x - mean) * rstd * g[c].x + be[c].x;
                float y1 = (v.y - mean) * rstd * g[c].y + be[c].y;
                float y2 = (v.z - mean) * rstd * g[c].z + be[c].z;
                float y3 = (v.w - mean) * rstd * g[c].w + be[c].w;
                halfx4 hi, lo;
                hi[0] = (_Float16)y0; lo[0] = (_Float16)(y0 - (float)hi[0]);
                hi[1] = (_Float16)y1; lo[1] = (_Float16)(y1 - (float)hi[1]);
                hi[2] = (_Float16)y2; lo[2] = (_Float16)(y2 - (float)hi[2]);
                hi[3] = (_Float16)y3; lo[3] = (_Float16)(y3 - (float)hi[3]);
                const int k0 = c * 256 + lane * 4;
                *(halfx4*)(&Ahi[r * APAD + k0]) = hi;
                *(halfx4*)(&Alo[r * APAD + k0]) = lo;
            }
        }
    }
    __syncthreads();

    // ---------- Phase 2: GEMM, barrier-free K loop, 2-pass A-split ----------
    // 13 N-tiles split {4,3,3,3}: wave0 -> 0..3, wave1 -> 4..6, wave2 -> 7..9,
    // wave3 -> 10..12. All 16 rows are one M-tile (MT==16).
    const int cnt  = (wv == 0) ? 4 : 3;
    const int nt0  = (wv == 0) ? 0 : (1 + 3 * wv);
    const int ln16 = lane & 15;
    const int q    = lane >> 4;

    f32x4 acc[4];
#pragma unroll
    for (int i = 0; i < 4; ++i) acc[i] = (f32x4){0.f, 0.f, 0.f, 0.f};

    int ncol[4], nload[4];
    float bs[4];
#pragma unroll
    for (int i = 0; i < 4; ++i) {
        const int n = (nt0 + i) * 16 + ln16;          // <= 207
        ncol[i]  = n;
        nload[i] = n < OUTN ? n : OUTN - 1;           // clamp: never read unwritten ws
        bs[i]    = (n < OUTN) ? bias[n] : 0.f;
    }

    const _Float16* Aph = &Ahi[ln16 * APAD + q * 8];
    const _Float16* Apl = &Alo[ln16 * APAD + q * 8];
#pragma unroll
    for (int kt = 0; kt < KT; ++kt) {
        const halfx8 ah = *(const halfx8*)(Aph + kt * 32);
        const halfx8 al = *(const halfx8*)(Apl + kt * 32);
#pragma unroll
        for (int i = 0; i < 4; ++i) {
            if (i < cnt) {
                const halfx8 bf = *(const halfx8*)(Wh + nload[i] * DD + kt * 32 + q * 8);
                acc[i] = __builtin_amdgcn_mfma_f32_16x16x32_f16(ah, bf, acc[i], 0, 0, 0);
                acc[i] = __builtin_amdgcn_mfma_f32_16x16x32_f16(al, bf, acc[i], 0, 0, 0);
            }
        }
    }

    // ---------- Epilogue: C/D layout col=lane&15, row=quad*4+reg ----------
    const long rbase = row0 + q * 4;
#pragma unroll
    for (int i = 0; i < 4; ++i) {
        if (i < cnt && ncol[i] < OUTN) {
#pragma unroll
            for (int rg = 0; rg < 4; ++rg)
                out[(rbase + rg) * OUTN + ncol[i]] = acc[i][rg] + bs[i];
        }
    }
}

extern "C" void kernel_launch(void* const* d_in, const int* in_sizes, int n_in,
                              void* d_out, int out_size, void* d_ws, size_t ws_size,
                              hipStream_t stream) {
    const float* x     = (const float*)d_in[0];
    const float* gamma = (const float*)d_in[1];
    const float* beta  = (const float*)d_in[2];
    const float* W     = (const float*)d_in[3];
    const float* b     = (const float*)d_in[4];
    float* out = (float*)d_out;
    _Float16* Wh = (_Float16*)d_ws;               // needs 196*768*2 = 301,056 B

    wprep_kernel<<<(OUTN * DD + 255) / 256, 256, 0, stream>>>(W, Wh);

    const long rows = 16L * 4096;                 // 65536
    fused_ln_linear<<<rows / MT, 256, 0, stream>>>(x, gamma, beta, Wh, b, out);
}

// Round 3
// 416.104 us; speedup vs baseline: 1.0422x; 1.0422x over previous
//
#include <hip/hip_runtime.h>

#define DD    768
#define OUTN  196
#define MT    16        // rows per block
#define KC    256       // K elems per stage (768 = 3 stages)
#define APAD  264       // fp16 row stride per stage buffer: dword stride 132 -> max 2-way bank aliasing (free, m136)
#define KTS   8         // MFMA k-steps per stage (256/32)

typedef __attribute__((ext_vector_type(8))) _Float16 halfx8;
typedef __attribute__((ext_vector_type(4))) _Float16 halfx4;
typedef __attribute__((ext_vector_type(4))) float    f32x4;

// W (196x768 fp32 row-major [n][k]) -> fp16, vectorized. [n][k] row-major is
// exactly the MFMA B^T fragment layout (8 consecutive k per lane).
__global__ __launch_bounds__(256) void wprep_kernel(const float4* __restrict__ W4,
                                                    halfx4* __restrict__ Wh4) {
    int i = blockIdx.x * 256 + threadIdx.x;
    if (i < OUTN * DD / 4) {
        float4 v = W4[i];
        halfx4 h;
        h[0] = (_Float16)v.x; h[1] = (_Float16)v.y;
        h[2] = (_Float16)v.z; h[3] = (_Float16)v.w;
        Wh4[i] = h;
    }
}

__global__ __launch_bounds__(256, 4) void fused_ln_linear(
    const float* __restrict__ x, const float* __restrict__ gamma,
    const float* __restrict__ beta, const _Float16* __restrict__ Wh,
    const float* __restrict__ bias, float* __restrict__ out)
{
    // Ping-pong stage buffers: 2 * (8448 + 8448) = 33,792 B -> 4 blocks/CU
    __shared__ _Float16 Ahi[2][MT * APAD];
    __shared__ _Float16 Alo[2][MT * APAD];

    const int tid  = threadIdx.x;
    const int wv   = tid >> 6;
    const int lane = tid & 63;
    const long row0 = (long)blockIdx.x * MT;
    const float* xrow = x + (row0 + wv * 4) * DD + lane * 4;

    // ---------- stats prepass: mean/rstd for this wave's 4 rows ----------
    float mean[4], rstd[4];
    {
        float s[4], ss[4];
#pragma unroll
        for (int t = 0; t < 4; ++t) { s[t] = 0.f; ss[t] = 0.f; }
#pragma unroll
        for (int t = 0; t < 4; ++t) {
#pragma unroll
            for (int c = 0; c < 3; ++c) {
                const float4 v = *(const float4*)(xrow + t * DD + c * KC);
                s[t]  += v.x + v.y + v.z + v.w;
                ss[t] += v.x * v.x + v.y * v.y + v.z * v.z + v.w * v.w;
            }
        }
#pragma unroll
        for (int t = 0; t < 4; ++t) {
#pragma unroll
            for (int off = 32; off > 0; off >>= 1) {
                s[t]  += __shfl_xor(s[t],  off);
                ss[t] += __shfl_xor(ss[t], off);
            }
            mean[t] = s[t] * (1.f / DD);
            const float var = ss[t] * (1.f / DD) - mean[t] * mean[t];
            rstd[t] = rsqrtf(var + 1e-6f);
        }
    }

    // ---------- N-tile assignment: 13 tiles split {4,3,3,3} ----------
    const int cnt  = (wv == 0) ? 4 : 3;
    const int nt0  = (wv == 0) ? 0 : (1 + 3 * wv);
    const int ln16 = lane & 15;
    const int q    = lane >> 4;

    int ncol[4], nload[4];
    float bs[4];
#pragma unroll
    for (int i = 0; i < 4; ++i) {
        const int n = (nt0 + i) * 16 + ln16;          // <= 207
        ncol[i]  = n;
        nload[i] = (n < OUTN ? n : OUTN - 1) * DD;    // clamp: never read past Wh
        bs[i]    = (n < OUTN) ? bias[n] : 0.f;
    }

    f32x4 acc[4];
#pragma unroll
    for (int i = 0; i < 4; ++i) acc[i] = (f32x4){0.f, 0.f, 0.f, 0.f};

    // ---------- stage helpers ----------
    auto stage_write = [&](int st, int buf) {
        const int k0 = st * KC + lane * 4;
        const float4 gv = *(const float4*)(gamma + k0);
        const float4 bv = *(const float4*)(beta + k0);
#pragma unroll
        for (int t = 0; t < 4; ++t) {
            const float4 v = *(const float4*)(xrow + t * DD + st * KC);
            const float y0 = (v.x - mean[t]) * rstd[t] * gv.x + bv.x;
            const float y1 = (v.y - mean[t]) * rstd[t] * gv.y + bv.y;
            const float y2 = (v.z - mean[t]) * rstd[t] * gv.z + bv.z;
            const float y3 = (v.w - mean[t]) * rstd[t] * gv.w + bv.w;
            halfx4 hi, lo;
            hi[0] = (_Float16)y0; lo[0] = (_Float16)(y0 - (float)hi[0]);
            hi[1] = (_Float16)y1; lo[1] = (_Float16)(y1 - (float)hi[1]);
            hi[2] = (_Float16)y2; lo[2] = (_Float16)(y2 - (float)hi[2]);
            hi[3] = (_Float16)y3; lo[3] = (_Float16)(y3 - (float)hi[3]);
            const int r = wv * 4 + t;
            *(halfx4*)(&Ahi[buf][r * APAD + lane * 4]) = hi;
            *(halfx4*)(&Alo[buf][r * APAD + lane * 4]) = lo;
        }
    };

    auto gemm_stage = [&](int st, int buf) {
        const _Float16* Aph = &Ahi[buf][ln16 * APAD + q * 8];
        const _Float16* Apl = &Alo[buf][ln16 * APAD + q * 8];
#pragma unroll
        for (int kt = 0; kt < KTS; ++kt) {
            const halfx8 ah = *(const halfx8*)(Aph + kt * 32);
            const halfx8 al = *(const halfx8*)(Apl + kt * 32);
#pragma unroll
            for (int i = 0; i < 4; ++i) {
                if (i < cnt) {
                    const halfx8 bf =
                        *(const halfx8*)(Wh + nload[i] + st * KC + kt * 32 + q * 8);
                    acc[i] = __builtin_amdgcn_mfma_f32_16x16x32_f16(ah, bf, acc[i], 0, 0, 0);
                    acc[i] = __builtin_amdgcn_mfma_f32_16x16x32_f16(al, bf, acc[i], 0, 0, 0);
                }
            }
        }
    };

    // ---------- pipelined stages: write(st+1) overlaps gemm(st) ----------
    stage_write(0, 0);
    __syncthreads();

    stage_write(1, 1);     // buffer 1: no reader yet, no barrier needed
    gemm_stage(0, 0);
    __syncthreads();       // all waves done reading buf0 + buf1 writes visible

    stage_write(2, 0);     // buf0's readers (gemm0) finished before the barrier
    gemm_stage(1, 1);
    __syncthreads();

    gemm_stage(2, 0);

    // ---------- epilogue: C/D layout col=lane&15, row=quad*4+reg ----------
    const long rbase = row0 + q * 4;
#pragma unroll
    for (int i = 0; i < 4; ++i) {
        if (i < cnt && ncol[i] < OUTN) {
#pragma unroll
            for (int rg = 0; rg < 4; ++rg)
                out[(rbase + rg) * OUTN + ncol[i]] = acc[i][rg] + bs[i];
        }
    }
}

extern "C" void kernel_launch(void* const* d_in, const int* in_sizes, int n_in,
                              void* d_out, int out_size, void* d_ws, size_t ws_size,
                              hipStream_t stream) {
    const float* x     = (const float*)d_in[0];
    const float* gamma = (const float*)d_in[1];
    const float* beta  = (const float*)d_in[2];
    const float* W     = (const float*)d_in[3];
    const float* b     = (const float*)d_in[4];
    float* out = (float*)d_out;
    _Float16* Wh = (_Float16*)d_ws;               // needs 196*768*2 = 301,056 B

    wprep_kernel<<<(OUTN * DD / 4 + 255) / 256, 256, 0, stream>>>(
        (const float4*)W, (halfx4*)Wh);

    const long rows = 16L * 4096;                 // 65536
    fused_ln_linear<<<rows / MT, 256, 0, stream>>>(x, gamma, beta, Wh, b, out);
}